// Round 1
// baseline (916.512 us; speedup 1.0000x reference)
//
#include <hip/hip_runtime.h>

// MoE: T=8192 tokens, D=1024, F=4096, E=8, top-2.
// Pipeline: cast/transpose weights to bf16 -> gate -> scatter to expert lists
// -> grouped GEMM1 (x@w1+b1, gelu) -> H -> grouped GEMM2 (H@w2+b2, *gate_wt,
// atomicAdd into out). ws usage ~286 MB.

#define T_TOK 8192
#define D_DIM 1024
#define F_DIM 4096
#define E_NUM 8
#define BM 128
#define BN 128
#define BK 32
#define MAX_TILES (T_TOK * 2 / BM + E_NUM)  // 136 worst case

typedef float f32x4 __attribute__((ext_vector_type(4)));
typedef short bf16x8 __attribute__((ext_vector_type(8)));

__device__ __forceinline__ unsigned short f2bf(float f) {
  union { float f; unsigned u; } v; v.f = f;
  unsigned r = v.u + 0x7FFFu + ((v.u >> 16) & 1u);  // RNE
  return (unsigned short)(r >> 16);
}

__device__ __forceinline__ void async_cp16(const unsigned short* g, unsigned short* l) {
  // 16B-wide global->LDS DMA. LDS dest is wave-uniform base + lane*16.
  __builtin_amdgcn_global_load_lds((__attribute__((address_space(1))) void*)g,
                                   (__attribute__((address_space(3))) void*)l,
                                   16, 0, 0);
}

// ---------------- small prep kernels ----------------

__global__ void cast_x_kernel(const float* __restrict__ src,
                              unsigned short* __restrict__ dst, int n4) {
  int i = blockIdx.x * blockDim.x + threadIdx.x;
  if (i >= n4) return;
  float4 v = ((const float4*)src)[i];
  ushort4 o;
  o.x = f2bf(v.x); o.y = f2bf(v.y); o.z = f2bf(v.z); o.w = f2bf(v.w);
  ((ushort4*)dst)[i] = o;
}

// src fp32 [R][C] row-major (per expert) -> dst bf16 [C][R]
__global__ void transpose_cast_kernel(const float* __restrict__ src,
                                      unsigned short* __restrict__ dst,
                                      int R, int C) {
  __shared__ float tile[64][65];  // +1 pad: conflict-free transposed reads
  int e = blockIdx.z;
  src += (size_t)e * R * C;
  dst += (size_t)e * R * C;
  int c0 = blockIdx.x * 64;
  int r0 = blockIdx.y * 64;
  int tc = threadIdx.x & 63, tr = threadIdx.x >> 6;  // 4 rows/pass
#pragma unroll
  for (int i = 0; i < 16; ++i) {
    int r = tr + i * 4;
    tile[r][tc] = src[(size_t)(r0 + r) * C + c0 + tc];
  }
  __syncthreads();
#pragma unroll
  for (int i = 0; i < 16; ++i) {
    int c = tr + i * 4;
    dst[(size_t)(c0 + c) * R + r0 + tc] = f2bf(tile[tc][c]);
  }
}

// one wave per token: logits = x[t] . gate_w[:,e], fp32; top-2 + softmax
__global__ __launch_bounds__(256) void gate_kernel(
    const float* __restrict__ x, const float* __restrict__ gw,
    float* __restrict__ topk_w, int* __restrict__ topk_e) {
  int t = (blockIdx.x * 256 + threadIdx.x) >> 6;
  int lane = threadIdx.x & 63;
  const float* xr = x + (size_t)t * D_DIM;
  float acc[8];
#pragma unroll
  for (int e = 0; e < 8; ++e) acc[e] = 0.f;
  for (int j = 0; j < D_DIM / 64; ++j) {
    int d = lane + 64 * j;
    float xv = xr[d];
    float4 g0 = ((const float4*)(gw + (size_t)d * 8))[0];
    float4 g1 = ((const float4*)(gw + (size_t)d * 8))[1];
    acc[0] += xv * g0.x; acc[1] += xv * g0.y;
    acc[2] += xv * g0.z; acc[3] += xv * g0.w;
    acc[4] += xv * g1.x; acc[5] += xv * g1.y;
    acc[6] += xv * g1.z; acc[7] += xv * g1.w;
  }
#pragma unroll
  for (int off = 32; off > 0; off >>= 1) {
#pragma unroll
    for (int e = 0; e < 8; ++e) acc[e] += __shfl_xor(acc[e], off);
  }
  if (lane == 0) {
    int e0 = 0; float v0 = acc[0];
#pragma unroll
    for (int e = 1; e < 8; ++e)
      if (acc[e] > v0) { v0 = acc[e]; e0 = e; }  // strict >: lowest index on tie
    int e1 = -1; float v1 = -1e30f;
#pragma unroll
    for (int e = 0; e < 8; ++e)
      if (e != e0 && acc[e] > v1) { v1 = acc[e]; e1 = e; }
    float ex = expf(v1 - v0);
    float inv = 1.f / (1.f + ex);
    topk_w[2 * t] = inv;
    topk_w[2 * t + 1] = ex * inv;
    topk_e[2 * t] = e0;
    topk_e[2 * t + 1] = e1;
  }
}

__global__ void scatter_kernel(const int* __restrict__ topk_e,
                               int* __restrict__ cnt, int* __restrict__ assign) {
  int idx = blockIdx.x * blockDim.x + threadIdx.x;  // (t,k) pair id = t*2+k
  int e = topk_e[idx];
  int pos = atomicAdd(&cnt[e], 1);
  assign[e * T_TOK + pos] = idx;
}

__global__ void tiles_kernel(const int* __restrict__ cnt,
                             int* __restrict__ ndesc, int4* __restrict__ desc) {
  if (threadIdx.x != 0) return;
  int nt = 0, hb = 0;
  for (int e = 0; e < E_NUM; ++e) {
    int c = cnt[e];
    for (int s = 0; s < c; s += BM) {
      int4 d;
      d.x = e; d.y = s; d.z = hb;
      d.w = (c - s < BM) ? (c - s) : BM;
      desc[nt++] = d;
    }
    hb += c;
  }
  *ndesc = nt;
}

// ---------------- grouped GEMMs ----------------
// m97 pattern: 128x128 tile, BK=32, global_load_lds(16B), 4 waves each 64x64,
// 16x mfma_f32_16x16x32_bf16 per K-step. LDS chunk swizzle (rotate 16B chunk by
// row) cuts frag-read bank conflicts 8-way -> ~4-way (can't pad: lds-DMA needs
// contiguous dest).

// GEMM1: H[slot][f] = gelu(x[tok] @ w1[e] + b1[e]);  A gathered via assign.
__global__ __launch_bounds__(256) void gemm1_kernel(
    const unsigned short* __restrict__ xb, const unsigned short* __restrict__ w1t,
    const float* __restrict__ b1, const int* __restrict__ assign,
    const int* __restrict__ ndesc, const int4* __restrict__ desc,
    unsigned short* __restrict__ H) {
  int tileid = blockIdx.y;
  if (tileid >= *ndesc) return;
  int4 dc = desc[tileid];
  int e = dc.x, start = dc.y, hbase = dc.z, mcnt = dc.w;
  int n0 = blockIdx.x * BN;  // f-offset

  __shared__ __attribute__((aligned(16))) unsigned short As[BM * BK];
  __shared__ __attribute__((aligned(16))) unsigned short Bs[BN * BK];

  int tid = threadIdx.x, lane = tid & 63, wv = tid >> 6;

  const unsigned short* gA[2]; const unsigned short* gB[2];
  unsigned short* lA[2]; unsigned short* lB[2];
#pragma unroll
  for (int s = 0; s < 2; ++s) {
    int L = tid + s * 256;           // 16B chunk id
    int row = L >> 2, cc = L & 3;
    int g = (cc - row) & 3;          // swizzle: LDS[row][cc] = glob[row][(cc-row)&3]
    int rowc = row < mcnt ? row : (mcnt - 1);
    int a = assign[e * T_TOK + start + rowc];
    gA[s] = xb + (size_t)(a >> 1) * D_DIM + g * 8;
    gB[s] = w1t + (size_t)(e * F_DIM + n0 + row) * D_DIM + g * 8;
    lA[s] = As + (size_t)(s * 256 + wv * 64) * 8;
    lB[s] = Bs + (size_t)(s * 256 + wv * 64) * 8;
  }

  int kc = lane >> 4, r16 = lane & 15;
  int m_off = (wv & 1) * 64, n_off = (wv >> 1) * 64;
  int aoff[4], boff[4];
#pragma unroll
  for (int i = 0; i < 4; ++i) {
    int ra = m_off + i * 16 + r16;
    aoff[i] = ra * 32 + ((kc + ra) & 3) * 8;
    int rb = n_off + i * 16 + r16;
    boff[i] = rb * 32 + ((kc + rb) & 3) * 8;
  }

  f32x4 acc[4][4];
#pragma unroll
  for (int i = 0; i < 4; ++i)
#pragma unroll
    for (int j = 0; j < 4; ++j) acc[i][j] = (f32x4){0.f, 0.f, 0.f, 0.f};

  for (int kt = 0; kt < D_DIM / BK; ++kt) {
#pragma unroll
    for (int s = 0; s < 2; ++s) {
      async_cp16(gA[s], lA[s]);
      async_cp16(gB[s], lB[s]);
      gA[s] += BK; gB[s] += BK;
    }
    __syncthreads();  // drains vmcnt (lds-DMA) before reads
    bf16x8 af[4], bfr[4];
#pragma unroll
    for (int i = 0; i < 4; ++i) af[i] = *(const bf16x8*)(As + aoff[i]);
#pragma unroll
    for (int i = 0; i < 4; ++i) bfr[i] = *(const bf16x8*)(Bs + boff[i]);
#pragma unroll
    for (int i = 0; i < 4; ++i)
#pragma unroll
      for (int j = 0; j < 4; ++j)
        acc[i][j] = __builtin_amdgcn_mfma_f32_16x16x32_bf16(af[i], bfr[j], acc[i][j], 0, 0, 0);
    __syncthreads();
  }

  // epilogue: C/D layout col=lane&15, row=(lane>>4)*4+reg
  int col = lane & 15, rbase = (lane >> 4) * 4;
  float bias[4];
#pragma unroll
  for (int j = 0; j < 4; ++j) bias[j] = b1[e * F_DIM + n0 + n_off + j * 16 + col];
#pragma unroll
  for (int i = 0; i < 4; ++i) {
#pragma unroll
    for (int rg = 0; rg < 4; ++rg) {
      int r = m_off + i * 16 + rbase + rg;
      if (r < mcnt) {
        unsigned short* hrow = H + (size_t)(hbase + start + r) * F_DIM + n0 + n_off + col;
#pragma unroll
        for (int j = 0; j < 4; ++j) {
          float v = acc[i][j][rg] + bias[j];
          v = 0.5f * v * (1.0f + erff(v * 0.70710678118654752f));  // exact gelu
          hrow[j * 16] = f2bf(v);
        }
      }
    }
  }
}

// GEMM2: out[tok] += wt * (H[slot] @ w2[e] + b2[e])
__global__ __launch_bounds__(256) void gemm2_kernel(
    const unsigned short* __restrict__ H, const unsigned short* __restrict__ w2t,
    const float* __restrict__ b2, const int* __restrict__ assign,
    const float* __restrict__ topk_w,
    const int* __restrict__ ndesc, const int4* __restrict__ desc,
    float* __restrict__ out) {
  int tileid = blockIdx.y;
  if (tileid >= *ndesc) return;
  int4 dc = desc[tileid];
  int e = dc.x, start = dc.y, hbase = dc.z, mcnt = dc.w;
  int n0 = blockIdx.x * BN;  // d-offset

  __shared__ __attribute__((aligned(16))) unsigned short As[BM * BK];
  __shared__ __attribute__((aligned(16))) unsigned short Bs[BN * BK];

  int tid = threadIdx.x, lane = tid & 63, wv = tid >> 6;

  const unsigned short* gA[2]; const unsigned short* gB[2];
  unsigned short* lA[2]; unsigned short* lB[2];
#pragma unroll
  for (int s = 0; s < 2; ++s) {
    int L = tid + s * 256;
    int row = L >> 2, cc = L & 3;
    int g = (cc - row) & 3;
    int rowc = row < mcnt ? row : (mcnt - 1);
    gA[s] = H + (size_t)(hbase + start + rowc) * F_DIM + g * 8;
    gB[s] = w2t + (size_t)(e * D_DIM + n0 + row) * F_DIM + g * 8;
    lA[s] = As + (size_t)(s * 256 + wv * 64) * 8;
    lB[s] = Bs + (size_t)(s * 256 + wv * 64) * 8;
  }

  int kc = lane >> 4, r16 = lane & 15;
  int m_off = (wv & 1) * 64, n_off = (wv >> 1) * 64;
  int aoff[4], boff[4];
#pragma unroll
  for (int i = 0; i < 4; ++i) {
    int ra = m_off + i * 16 + r16;
    aoff[i] = ra * 32 + ((kc + ra) & 3) * 8;
    int rb = n_off + i * 16 + r16;
    boff[i] = rb * 32 + ((kc + rb) & 3) * 8;
  }

  f32x4 acc[4][4];
#pragma unroll
  for (int i = 0; i < 4; ++i)
#pragma unroll
    for (int j = 0; j < 4; ++j) acc[i][j] = (f32x4){0.f, 0.f, 0.f, 0.f};

  for (int kt = 0; kt < F_DIM / BK; ++kt) {
#pragma unroll
    for (int s = 0; s < 2; ++s) {
      async_cp16(gA[s], lA[s]);
      async_cp16(gB[s], lB[s]);
      gA[s] += BK; gB[s] += BK;
    }
    __syncthreads();
    bf16x8 af[4], bfr[4];
#pragma unroll
    for (int i = 0; i < 4; ++i) af[i] = *(const bf16x8*)(As + aoff[i]);
#pragma unroll
    for (int i = 0; i < 4; ++i) bfr[i] = *(const bf16x8*)(Bs + boff[i]);
#pragma unroll
    for (int i = 0; i < 4; ++i)
#pragma unroll
      for (int j = 0; j < 4; ++j)
        acc[i][j] = __builtin_amdgcn_mfma_f32_16x16x32_bf16(af[i], bfr[j], acc[i][j], 0, 0, 0);
    __syncthreads();
  }

  int col = lane & 15, rbase = (lane >> 4) * 4;
  float bias[4];
#pragma unroll
  for (int j = 0; j < 4; ++j) bias[j] = b2[e * D_DIM + n0 + n_off + j * 16 + col];
#pragma unroll
  for (int i = 0; i < 4; ++i) {
#pragma unroll
    for (int rg = 0; rg < 4; ++rg) {
      int r = m_off + i * 16 + rbase + rg;
      if (r < mcnt) {
        int a = assign[e * T_TOK + start + r];
        float wt = topk_w[a];
        float* orow = out + (size_t)(a >> 1) * D_DIM + n0 + n_off + col;
#pragma unroll
        for (int j = 0; j < 4; ++j) {
          float v = acc[i][j][rg] + bias[j];
          atomicAdd(orow + j * 16, wt * v);  // 2 contenders/address
        }
      }
    }
  }
}

// ---------------- launcher ----------------

extern "C" void kernel_launch(void* const* d_in, const int* in_sizes, int n_in,
                              void* d_out, int out_size, void* d_ws, size_t ws_size,
                              hipStream_t stream) {
  const float* x      = (const float*)d_in[0];
  const float* gate_w = (const float*)d_in[1];
  const float* w1     = (const float*)d_in[2];
  const float* b1     = (const float*)d_in[3];
  const float* w2     = (const float*)d_in[4];
  const float* b2     = (const float*)d_in[5];
  float* out = (float*)d_out;

  char* ws = (char*)d_ws;
  size_t off = 0;
  auto alloc = [&](size_t bytes) {
    char* p = ws + off;
    off = (off + bytes + 255) & ~(size_t)255;
    return p;
  };
  unsigned short* xb   = (unsigned short*)alloc((size_t)T_TOK * D_DIM * 2);
  unsigned short* w1t  = (unsigned short*)alloc((size_t)E_NUM * D_DIM * F_DIM * 2);
  unsigned short* w2t  = (unsigned short*)alloc((size_t)E_NUM * D_DIM * F_DIM * 2);
  unsigned short* Hbuf = (unsigned short*)alloc((size_t)2 * T_TOK * F_DIM * 2);
  float* topk_w = (float*)alloc((size_t)2 * T_TOK * 4);
  int* topk_e   = (int*)alloc((size_t)2 * T_TOK * 4);
  int* assign   = (int*)alloc((size_t)E_NUM * T_TOK * 4);
  int* cnt      = (int*)alloc(64);
  int* ndesc    = (int*)alloc(64);
  int4* desc    = (int4*)alloc((size_t)MAX_TILES * 16);

  hipMemsetAsync(cnt, 0, 64, stream);
  hipMemsetAsync(out, 0, (size_t)out_size * 4, stream);

  cast_x_kernel<<<(T_TOK * D_DIM / 4 + 255) / 256, 256, 0, stream>>>(
      x, xb, T_TOK * D_DIM / 4);
  transpose_cast_kernel<<<dim3(F_DIM / 64, D_DIM / 64, E_NUM), 256, 0, stream>>>(
      w1, w1t, D_DIM, F_DIM);  // [D][F] -> [F][D]
  transpose_cast_kernel<<<dim3(D_DIM / 64, F_DIM / 64, E_NUM), 256, 0, stream>>>(
      w2, w2t, F_DIM, D_DIM);  // [F][D] -> [D][F]
  gate_kernel<<<T_TOK / 4, 256, 0, stream>>>(x, gate_w, topk_w, topk_e);
  scatter_kernel<<<2 * T_TOK / 256, 256, 0, stream>>>(topk_e, cnt, assign);
  tiles_kernel<<<1, 64, 0, stream>>>(cnt, ndesc, desc);
  gemm1_kernel<<<dim3(F_DIM / BN, MAX_TILES), 256, 0, stream>>>(
      xb, w1t, b1, assign, ndesc, desc, Hbuf);
  gemm2_kernel<<<dim3(D_DIM / BN, MAX_TILES), 256, 0, stream>>>(
      Hbuf, w2t, b2, assign, topk_w, ndesc, desc, out);
}